// Round 3
// baseline (559.912 us; speedup 1.0000x reference)
//
#include <hip/hip_runtime.h>
#include <math.h>

// Problem constants (setup_inputs: N=32, C=1, W=512, L=512)
#define WD 512          // image / detector width
#define PF 1024         // FFT pad length
#define LH2 1028        // shifted ramp-kernel table length

// Workspace layout (float offsets). ws bytes: 16 KB + 33.55 MB table.
#define OFF_H2 0        // 1028 floats
#define OFF_ANG 2048    // 512 x float4 (chw, shw, wB, iA-bits)
#define OFF_PK 4096     // packed fp16 sinogram: [g][l][s] uint4 (4 imgs x (y[s],y[s+1]))

#define GOFF 107        // LDS slot = detector_index + GOFF (guards absorb out-of-circle idx)
#define GSLOTS 726      // covers idx in [-107, 618]

typedef __fp16 half2_t __attribute__((ext_vector_type(2)));

__device__ __forceinline__ half2_t pkh(float a, float b) {
  return __builtin_amdgcn_cvt_pkrtz(a, b);   // v_cvt_pkrtz_f16_f32
}
__device__ __forceinline__ unsigned pkbits(float a, float b) {
  return __builtin_bit_cast(unsigned, pkh(a, b));
}
__device__ __forceinline__ float dot2f(unsigned tapbits, half2_t w, float c) {
  half2_t tp = __builtin_bit_cast(half2_t, tapbits);
  return __builtin_amdgcn_fdot2(tp, w, c, false);   // v_dot2_f32_f16
}
// Bank swizzle: stride-8/16-float lanes -> stride 9/18 mod 32 (<=2-way = free).
__device__ __forceinline__ int hsw(int i) { return i + (i >> 3); }

__device__ __forceinline__ float t2(int p) {
  return (float)(-1.0 + 2.0 * (double)p / (double)(WD - 1));
}

// Async global->LDS, 16 B per lane. HW semantics (m104): LDS dest is
// wave-uniform base + lane*16; global src is per-lane. Our staging layout is
// exactly that (sA = t&511 contiguous per wave, p wave-uniform, linear dest).
__device__ __forceinline__ void gload_lds16(const void* g, void* l) {
  __builtin_amdgcn_global_load_lds(
      (const __attribute__((address_space(1))) unsigned*)g,
      (__attribute__((address_space(3))) unsigned*)l, 16, 0, 0);
}

// ---------------------------------------------------------------------------
// Setup: h2[i] = h[(i-512) & 1023] via v_cos (arg in REVOLUTIONS).
// h has EXACT zeros at all even offsets d != 0 (triangle spectrum 2|f|
// frequency-sampled with even P). filter_kernel consumes only the odd taps +
// the d=0 center tap; the table stays full-length so the compressed view
// h2[2t+1] / h2[512] can be loaded from it.
// ---------------------------------------------------------------------------
__global__ void setup_kernel(const float* __restrict__ theta,
                             float* __restrict__ ws, int L) {
  int gid = blockIdx.x * blockDim.x + threadIdx.x;
  if (gid < LH2) {
    int dd = gid - (PF / 2);
    if (dd < 0) dd = -dd;
    float acc = 0.f;
    for (int k = 0; k < PF; ++k) {
      int kk = (k <= PF / 2) ? k : (PF - k);
      float filt = 2.f * (float)kk * (1.f / (float)PF);
      int m = (k * dd) & (PF - 1);            // phase in [0,1) revolutions
#if __has_builtin(__builtin_amdgcn_cosf)
      float cv = __builtin_amdgcn_cosf((float)m * (1.f / (float)PF));
#else
      float cv = cosf((float)m * (6.28318530717958647692f / (float)PF));
#endif
      acc = fmaf(filt, cv, acc);
    }
    ws[OFF_H2 + gid] = acc * (1.f / (float)PF);
  } else if (gid < LH2 + L) {
    int l = gid - LH2;
    double rad = (double)theta[l] * 0.017453292519943295;
    const float hw = 0.5f * (float)(WD - 1);
    float cx = (float)l * (float)((double)(WD - 1) / (double)(L - 1));
    float c0 = floorf(cx);
    float wc = cx - c0;
    int ia = (int)c0;
    float ok = (ia + 1 <= WD - 1) ? 1.f : 0.f;
    float4 a;
    a.x = (float)cos(rad) * hw;
    a.y = (float)sin(rad) * hw;
    a.z = wc * ok;                       // wB (0 when L==WD: cx = l exactly)
    a.w = __int_as_float(ia);
    ((float4*)(ws + OFF_ANG))[l] = a;
  }
}

// ---------------------------------------------------------------------------
// Ramp filter -> packed fp16 table. v2: odd-taps-only convolution.
// out[s] = h0*x[s] + sum_{odd d} h[d]*x[s-d]. m processed in PAIRS with a
// 9-wide rolling window over the compressed odd-tap table ho[t] = h2[2t+1].
// FMAs per thread: 8192. 256 threads, 16 l x 512 r, 2x16 microtile, 4 blk/CU.
// ---------------------------------------------------------------------------
__global__ __launch_bounds__(256, 4) void filter_kernel(
    const float* __restrict__ x, const float* __restrict__ ws,
    unsigned char* __restrict__ pk) {
  __shared__ float hol[584];                    // odd taps, swizzled, +2 front guard
  __shared__ __align__(16) float bxl[64][20];   // [m][l], 16 l + 4 pad
  const int t = threadIdx.x;
  const int tx = t & 31, ty = t >> 5;          // tx: r/16 (0..31), ty: l/2 (0..7)
  const int n = blockIdx.y;
  const int g = n >> 2, k = n & 3;
  const int l0 = blockIdx.x << 4;

  for (int i = t; i < 512; i += 256) hol[2 + hsw(i)] = ws[OFF_H2 + 2 * i + 1];
  const float h0 = ws[OFF_H2 + 512];           // center tap (broadcast load)

  float acc[2][16] = {};
  const float* __restrict__ xn = x + (size_t)n * WD * WD;
  const int first = tx << 4;
  const int cchunk = first & ~63;              // chunk holding rows first..first+15

  for (int mc = 0; mc < WD; mc += 64) {
    __syncthreads();
    {                                          // stage x[mc..mc+63][l0..l0+15]
      int row = t >> 2;
      int c4 = (t & 3) << 2;
      float4 v = *(const float4*)(xn + (size_t)(mc + row) * WD + l0 + c4);
      *(float4*)(&bxl[row][c4]) = v;
    }
    __syncthreads();
    const int tb = (first + 512 - mc) >> 1;    // rbase/2 (rbase always even)
    float w[9];
#pragma unroll
    for (int j = 0; j < 9; ++j) w[j] = hol[2 + hsw(tb - 1 + j)];
    if (mc == cchunk) {                        // center tap h0 * x[s]
      const int rloc = first & 63;
#pragma unroll
      for (int j = 0; j < 16; ++j) {
        float2 cv = *(const float2*)(&bxl[rloc + j][ty << 1]);
        acc[0][j] = fmaf(h0, cv.x, acc[0][j]);
        acc[1][j] = fmaf(h0, cv.y, acc[1][j]);
      }
    }
    for (int mb = 0; mb < 64; mb += 8) {       // 4 m-pairs per batch
      float nh4[4];
      float2 bv8[8];
#pragma unroll
      for (int kk = 0; kk < 8; ++kk)           // batch LDS loads (indep)
        bv8[kk] = *(const float2*)(&bxl[mb + kk][ty << 1]);
#pragma unroll
      for (int kk = 0; kk < 4; ++kk)
        nh4[kk] = hol[2 + hsw(tb - (mb >> 1) - kk - 2)];  // hsw(-1)+2 == 0: safe
#pragma unroll
      for (int kk = 0; kk < 4; ++kk) {
        float2 xe = bv8[2 * kk], xo = bv8[2 * kk + 1];
#pragma unroll
        for (int b = 0; b < 8; ++b) {
          acc[0][2 * b + 1] = fmaf(xe.x, w[b + 1], acc[0][2 * b + 1]);
          acc[1][2 * b + 1] = fmaf(xe.y, w[b + 1], acc[1][2 * b + 1]);
          acc[0][2 * b]     = fmaf(xo.x, w[b],     acc[0][2 * b]);
          acc[1][2 * b]     = fmaf(xo.y, w[b],     acc[1][2 * b]);
        }
#pragma unroll
        for (int j = 8; j > 0; --j) w[j] = w[j - 1];   // renamed by unroll
        w[0] = nh4[kk];
      }
    }
  }

  // Epilogue: scatter into interleaved pk table (byte lane k, group g).
#pragma unroll
  for (int li = 0; li < 2; ++li) {
    int l = l0 + (ty << 1) + li;
    size_t rowb = ((size_t)(g * 512 + l) * 512) * 16 + (size_t)(k << 2);
#pragma unroll
    for (int j = 0; j < 15; ++j) {             // full entries s = first..first+14
      unsigned d = pkbits(acc[li][j], acc[li][j + 1]);
      *(unsigned*)(pk + rowb + (size_t)(first + j) * 16) = d;
    }
    unsigned lastp = pkbits(acc[li][15], 0.f);
    if (first + 15 == 511) {
      *(unsigned*)(pk + rowb + (size_t)511 * 16) = lastp;     // hi half must be 0
    } else {
      *(unsigned short*)(pk + rowb + (size_t)(first + 15) * 16) = (unsigned short)lastp;
    }
    if (first > 0) {                            // hi half of entry s = first-1
      unsigned fh = pkbits(acc[li][0], 0.f);
      *(unsigned short*)(pk + rowb + (size_t)(first - 1) * 16 + 2) = (unsigned short)fh;
    }
  }
}

// ---------------------------------------------------------------------------
// Backprojection v8: v6 structure (1024 threads, 64x64 px x 4 imgs, 2 angles
// per round, ONE barrier per round) with two DS-issue cuts:
//  1. Staging via global_load_lds (TA-port writes LDS directly): removes the
//     16 ds_write_b128 wave-instrs/angle/CU from the DS issue pipe (144->128,
//     -11%). Prefetch for round r+1 is issued right AFTER the round-r barrier
//     and drained by the round-r END barrier (full compute phase in flight,
//     m97 steady-state pattern — no drain stall). Layout satisfies the HW
//     constraint: LDS dest = wave-uniform base + lane*16, linear, guards
//     outside the written range. NOTE: gll path assumes wB==0 (exact for
//     L==W: cx = l). DS-pipe model: 128 ds_read_b128 x ~12cy/angle/CU.
//  2. Wave-strip circle skip (angle-independent, wave-uniform): a wave owns a
//     4-row x 64-col strip; if fully outside the circle, skip accumulation
//     (still stage + barrier). ~3% fewer gathers in edge tiles.
// v7 post-mortem kept: vector-memory gathers are cache-line-serial (~26cy) —
// LDS is the only high-throughput gather engine. Do not re-try.
// ---------------------------------------------------------------------------
__device__ __forceinline__ void accum_angle(const uint4* __restrict__ br,
                                            float4 a, float tiv,
                                            const float* __restrict__ tjv,
                                            float hw, float acc[4][4]) {
  const float chw = a.x, shw = a.y;
  float bi = fmaf(tiv, -shw, hw);
#pragma unroll
  for (int dj = 0; dj < 4; ++dj) {
    float ry = fmaf(tjv[dj], chw, bi);
    int idx = (int)ry;                   // trunc; OOB lands in zero guards
    float w1 = ry - (float)idx;
    half2_t wpk = pkh(1.f - w1, w1);
    uint4 q = br[idx + GOFF];            // one ds_read_b128 serves 4 images
    acc[dj][0] = dot2f(q.x, wpk, acc[dj][0]);
    acc[dj][1] = dot2f(q.y, wpk, acc[dj][1]);
    acc[dj][2] = dot2f(q.z, wpk, acc[dj][2]);
    acc[dj][3] = dot2f(q.w, wpk, acc[dj][3]);
  }
}

__global__ __launch_bounds__(1024, 8) void backproj_kernel(
    const float* __restrict__ ws, const unsigned char* __restrict__ pk,
    float* __restrict__ out, int L) {
  __shared__ __align__(16) uint4 buf[2][2][GSLOTS];   // [round parity][angle][slot]
  const int t = threadIdx.x;
  const int tx = t & 15, ty = t >> 4;        // ty: 0..63 (full i of tile)
  const int j0 = (blockIdx.x & 7) << 6;
  const int i0 = (blockIdx.x >> 3) << 6;
  const int g = blockIdx.y;
  const int n0 = g << 2;

  const float tiv = t2(i0 + ty);
  float tjv[4];
#pragma unroll
  for (int a = 0; a < 4; ++a) tjv[a] = t2(j0 + tx + 16 * a);

  // Corner-tile skip: entire 64x64 tile outside the circle -> zeros, no compute.
  {
    float il = t2(i0), ih = t2(i0 + 63);
    float jl = t2(j0), jh = t2(j0 + 63);
    float mi = (il <= 0.f && ih >= 0.f) ? 0.f : fminf(fabsf(il), fabsf(ih));
    float mj = (jl <= 0.f && jh >= 0.f) ? 0.f : fminf(fabsf(jl), fabsf(jh));
    if (mi * mi + mj * mj > 1.f) {
#pragma unroll
      for (int k = 0; k < 4; ++k) {
        float* ob = out + (size_t)(n0 + k) * WD * WD + (size_t)(i0 + ty) * WD;
#pragma unroll
        for (int dj = 0; dj < 4; ++dj) ob[j0 + tx + 16 * dj] = 0.f;
      }
      return;
    }
  }

  // Wave-strip skip (wave-uniform): this wave's 4 i-rows x full 64-col strip.
  bool stripOut;
  {
    int ib = i0 + (ty & ~3);
    float il = t2(ib), ih = t2(ib + 3);
    float jl = t2(j0), jh = t2(j0 + 63);
    float mi = (il <= 0.f && ih >= 0.f) ? 0.f : fminf(fabsf(il), fabsf(ih));
    float mj = (jl <= 0.f && jh >= 0.f) ? 0.f : fminf(fabsf(jl), fabsf(jh));
    stripOut = (mi * mi + mj * mj > 1.f);
  }

  const float4* __restrict__ angp = (const float4*)(ws + OFF_ANG);
  const unsigned char* gb = pk + (size_t)g * (512 * 512 * 16);

  for (int s = t; s < 2 * 2 * GSLOTS; s += 1024)
    ((uint4*)buf)[s] = make_uint4(0u, 0u, 0u, 0u);
  __syncthreads();                       // guards visible before first staging

  const float hw = 0.5f * (float)(WD - 1);
  float acc[4][4] = {};                  // [dj][img]

  const int sA = t & 511;                // staged slot
  const int p = t >> 9;                  // which of the round's 2 angles we stage

  float4 aA = angp[0];
  float4 aB = angp[L > 1 ? 1 : 0];

  // Round-0 staging (async, drained by the next barrier).
  {
    float4 a0 = p ? aB : aA;
    const unsigned char* src =
        gb + (size_t)__float_as_int(a0.w) * (512 * 16) + (size_t)sA * 16;
    gload_lds16(src, &buf[0][p][GOFF + sA]);
  }
  __syncthreads();                       // vmcnt drained -> buf[0] ready

  const int rounds = (L + 1) >> 1;
  for (int r = 0; r < rounds; ++r) {
    const int rp = r & 1;
    int na = 2 * r + 2, nb = 2 * r + 3;
    float4 aA2 = angp[na < L ? na : L - 1];
    float4 aB2 = angp[nb < L ? nb : L - 1];
    if (r + 1 < rounds) {                // prefetch round r+1 into buf[rp^1];
      float4 an = p ? aB2 : aA2;         // in flight across the whole compute
      const unsigned char* src =
          gb + (size_t)__float_as_int(an.w) * (512 * 16) + (size_t)sA * 16;
      gload_lds16(src, &buf[rp ^ 1][p][GOFF + sA]);
    }

    if (!stripOut) {
      accum_angle(&buf[rp][0][0], aA, tiv, tjv, hw, acc);
      if (2 * r + 1 < L)
        accum_angle(&buf[rp][1][0], aB, tiv, tjv, hw, acc);
    }
    __syncthreads();                     // readers done with buf[rp]; prefetch landed
    aA = aA2; aB = aB2;
  }

  const float scale = (float)(3.14159265358979323846 / (2.0 * (double)L));
#pragma unroll
  for (int k = 0; k < 4; ++k) {
    float* ob = out + (size_t)(n0 + k) * WD * WD + (size_t)(i0 + ty) * WD;
#pragma unroll
    for (int dj = 0; dj < 4; ++dj) {
      float rr = tiv * tiv + tjv[dj] * tjv[dj];
      ob[j0 + tx + 16 * dj] = (rr <= 1.f) ? acc[dj][k] * scale : 0.f;
    }
  }
}

extern "C" void kernel_launch(void* const* d_in, const int* in_sizes, int n_in,
                              void* d_out, int out_size, void* d_ws, size_t ws_size,
                              hipStream_t stream) {
  const float* x = (const float*)d_in[0];
  const float* theta = (const float*)d_in[1];
  float* out = (float*)d_out;
  float* ws = (float*)d_ws;
  int L = in_sizes[1];                       // 512
  int NC = in_sizes[0] / (WD * WD);          // 32
  unsigned char* pk = (unsigned char*)(ws + OFF_PK);

  int nset = LH2 + L;
  hipLaunchKernelGGL(setup_kernel, dim3((nset + 255) / 256), dim3(256), 0, stream,
                     theta, ws, L);
  hipLaunchKernelGGL(filter_kernel, dim3(32, NC), dim3(256), 0, stream,
                     x, ws, pk);
  hipLaunchKernelGGL(backproj_kernel, dim3(64, NC / 4), dim3(1024), 0, stream,
                     ws, pk, out, L);
}